// Round 9
// baseline (34.514 us; speedup 1.0000x reference)
//
#include <hip/hip_runtime.h>

// BernsteinSplineCouplingBlock: BATCH=65536, CHANNELS=64, SPLIT1=SPLIT2=32, DEGREE=10
// out[:, :32] = x[:, :32]
// s = x1 @ W.T + b  -> [B*32, 12]; spline(s, x2) -> out[:, 32:]
// GEMM via split-bf16 (hi+lo) 3-MFMA chain for ~f32 precision.
// R9: MFMA operand swap (A=W, B=x  ->  D[out][batch]): same per-lane loads,
//     but C-scatter becomes ONE ds_write_b128 per tile (24 scalar -> 6 vector
//     LDS writes per half) and bias C-in becomes a f32x4 vector load.

typedef short v8s  __attribute__((ext_vector_type(8)));  // 8 x bf16 (4 VGPRs)
typedef float f32x4 __attribute__((ext_vector_type(4)));
typedef float f32x2 __attribute__((ext_vector_type(2)));

#define LOG2E 1.44269504088896340736f
#define LN2   0.69314718055994530942f

__device__ __forceinline__ short f2bf(float f) {
    union { float f; unsigned u; } v; v.f = f;
    return (short)((v.u + 0x7FFFu + ((v.u >> 16) & 1u)) >> 16);  // RNE
}

__device__ __forceinline__ float bf2f(short h) {
    union { unsigned u; float f; } v; v.u = ((unsigned)(unsigned short)h) << 16;
    return v.f;
}

__device__ __forceinline__ float sgn01(float x) {
    return (x > 0.f) ? 1.f : ((x < 0.f) ? -1.f : 0.f);
}

// log2-domain softplus: softplus(x)/ln2  (mul, v_exp, add, v_log)
__device__ __forceinline__ float softplus_l2(float x) {
    return __log2f(1.0f + exp2f(x * LOG2E));
}

// Horner-Bernstein spline. sv[0..9] raw coeffs, sv[10] width, sv[11] height.
__device__ __forceinline__ float spline_horner(const float* sv, float xf) {
    // cumsum(softplus) in log2 units; ln2 cancels under inv-normalization.
    float spv[10], cn_[11];
    cn_[0] = 0.f;
    float run = 0.f;
#pragma unroll
    for (int j = 0; j < 10; ++j) {
        spv[j] = softplus_l2(sv[j]);
        run += spv[j];
        cn_[j + 1] = run;
    }
    const float inv = __fdividef(1.f, run);

    const float wd = fmaf(LN2, softplus_l2(sv[10]), 0.1f);  // softplus>0 => +0.1
    float hg = sv[11];
    hg += 0.1f * sgn01(hg);

    const float t  = __fdividef(xf, wd) + 0.5f;
    const float tc = fminf(fmaxf(t, 0.f), 1.f);
    const float s  = 1.f - tc;

    // P = sum_{i=1..10} C10_i cn_[i] tc^i s^(10-i)   (value, unnormalized)
    // Q = sum_{i=0..9}  C9_i  spv[i] tc^i s^(9-i)    (deriv/10, unnormalized)
    const float C10[11] = {1.f,10.f,45.f,120.f,210.f,252.f,210.f,120.f,45.f,10.f,1.f};
    const float C9[10]  = {1.f,9.f,36.f,84.f,126.f,126.f,84.f,36.f,9.f,1.f};
    float tk = 1.f, P = 0.f, Q = 0.f;
#pragma unroll
    for (int i = 0; i < 10; ++i) {
        Q = fmaf(Q, s, tk * (C9[i] * spv[i]));
        P = fmaf(P, s, tk * (C10[i] * cn_[i]));   // i=0 term folds to 0
        tk *= tc;
    }
    P = fmaf(P, s, tk * cn_[10]);                 // i=10, C(10,10)=1

    const float der = 10.f * Q * inv;
    const float ym  = P * inv;
    float y = (t < 0.f) ? (t * der)
            : ((t > 1.f) ? fmaf(t - 1.f, der, 1.f) : ym);
    return (y - 0.5f) * hg;
}

// fallback math (R3-proven de Casteljau)
__device__ __forceinline__ float softplus_f(float x) {
    return __logf(1.0f + __expf(x));
}
__device__ __forceinline__ float spline_eval(const float* sv, float xf) {
    float cn[11];
    cn[0] = 0.f;
    float run = 0.f;
#pragma unroll
    for (int j = 0; j < 10; ++j) { run += softplus_f(sv[j]); cn[j + 1] = run; }
    const float inv = __fdividef(1.f, run);
    const float wd = softplus_f(sv[10]) + 0.1f;
    float hg = sv[11];
    hg += 0.1f * sgn01(hg);
    const float t   = __fdividef(xf, wd) + 0.5f;
    const float tc  = fminf(fmaxf(t, 0.f), 1.f);
#pragma unroll
    for (int n = 10; n >= 2; --n) {
#pragma unroll
        for (int i = 0; i < n; ++i) cn[i] += tc * (cn[i + 1] - cn[i]);
    }
    const float db    = cn[1] - cn[0];
    const float deriv = 10.f * db * inv;
    const float ym    = fmaf(tc, db, cn[0]) * inv;
    float y = (t < 0.f) ? (t * deriv)
            : ((t > 1.f) ? fmaf(t - 1.f, deriv, 1.f) : ym);
    return (y - 0.5f) * hg;
}

// ---- prep: split W f32 -> bf16 hi/lo in fragment order ----
// frag layout: [(k>>3)*3072 + out*8 + (k&7)], hi at wsH, lo at wsL
// (serves as A-frag for W after the operand swap: lane m=l&15 -> out, k=(l>>4)*8+e)
__global__ void prep_w(const float* __restrict__ W, short* __restrict__ wsH,
                       short* __restrict__ wsL) {
    const int g = blockIdx.x * 256 + threadIdx.x;
    if (g < 12288) {
        const int o = g >> 5;        // W row (out index 0..383)
        const int k = g & 31;
        const float w = W[g];
        const short hi = f2bf(w);
        const int off = (k >> 3) * 3072 + o * 8 + (k & 7);
        wsH[off] = hi;
        wsL[off] = f2bf(w - bf2f(hi));
    }
}

// ---- main: 2048 blocks = (row group) x (channel half), 4 waves, no barriers ----
__global__ __launch_bounds__(256) void bern_spline_fast(
    const float* __restrict__ x, const short* __restrict__ wsH,
    const short* __restrict__ wsL, const float* __restrict__ bias,
    float* __restrict__ out)
{
    __shared__ __align__(16) float sl[4 * 16 * 100];  // per-wave 16 rows x (96+4pad), 25.6 KB

    const int tid  = threadIdx.x;
    const int wave = tid >> 6;
    const int lane = tid & 63;
    const int cbit = blockIdx.x & 1;            // channel half: ch in [cbit*16, +16)
    const int block_row = (blockIdx.x >> 1) * 64;

    const int row16 = lane & 15;
    const int kq    = lane >> 4;
    const int arow  = block_row + wave * 16 + row16;

    // xf pairs for both halves — issued first, consumed deep in spline phase
    const int cg0_h0 = cbit * 16 + 2 * kq;
    const f32x2 xf2_0 = *(const f32x2*)(x + (size_t)arow * 64 + 32 + cg0_h0);
    const f32x2 xf2_1 = *(const f32x2*)(x + (size_t)arow * 64 + 32 + cg0_h0 + 8);

    // x fragment (B operand after swap): lane holds x1[batch=l&15][k=(l>>4)*8..+7]
    const f32x4 a0 = *(const f32x4*)(x + (size_t)arow * 64 + kq * 8);
    const f32x4 a1 = *(const f32x4*)(x + (size_t)arow * 64 + kq * 8 + 4);
    v8s ah, al;
#pragma unroll
    for (int e = 0; e < 4; ++e) {
        const short h0 = f2bf(a0[e]);
        ah[e] = h0;     al[e] = f2bf(a0[e] - bf2f(h0));
        const short h1 = f2bf(a1[e]);
        ah[e + 4] = h1; al[e + 4] = f2bf(a1[e] - bf2f(h1));
    }

    float* swv = sl + wave * 1600;   // wave-private transpose buffer

    // ---- W-frag loads half 0 (A operand) ----
    v8s bh0[6], bl0[6];
#pragma unroll
    for (int ot = 0; ot < 6; ++ot) {
        const int boff = kq * 3072 + ((cbit * 12 + ot) * 16 + row16) * 8;
        bh0[ot] = *(const v8s*)(wsH + boff);
        bl0[ot] = *(const v8s*)(wsL + boff);
    }

    // ---- MFMA half 0: D[out][batch]; bias C-in as f32x4 (outs 4kq..4kq+3) ----
    // lane holds D rows (out) 4*kq+r for batch col row16 -> ONE b128 LDS store/tile
#pragma unroll
    for (int ot = 0; ot < 6; ++ot) {
        const f32x4 cb = *(const f32x4*)(bias + (cbit * 12 + ot) * 16 + 4 * kq);
        f32x4 c = __builtin_amdgcn_mfma_f32_16x16x32_bf16(bh0[ot], al, cb, 0, 0, 0);
        c = __builtin_amdgcn_mfma_f32_16x16x32_bf16(bl0[ot], ah, c, 0, 0, 0);
        c = __builtin_amdgcn_mfma_f32_16x16x32_bf16(bh0[ot], ah, c, 0, 0, 0);
        *(f32x4*)(swv + row16 * 100 + ot * 16 + 4 * kq) = c;
    }

    // ---- PREFETCH: W-frag loads half 1 (in flight during half-0 splines) ----
    v8s bh1[6], bl1[6];
#pragma unroll
    for (int ot = 0; ot < 6; ++ot) {
        const int boff = kq * 3072 + ((cbit * 12 + 6 + ot) * 16 + row16) * 8;
        bh1[ot] = *(const v8s*)(wsH + boff);
        bl1[ot] = *(const v8s*)(wsL + boff);
    }

    // ---- splines: lane = (row16=batch, channel pair 2*kq, 2*kq+1) per half ----
#pragma unroll
    for (int hf = 0; hf < 2; ++hf) {
        if (hf == 1) {
            // MFMA half 1 + b128 LDS store (prefetched W-frags)
#pragma unroll
            for (int ot = 0; ot < 6; ++ot) {
                const f32x4 cb = *(const f32x4*)(bias + (cbit * 12 + 6 + ot) * 16 + 4 * kq);
                f32x4 c = __builtin_amdgcn_mfma_f32_16x16x32_bf16(bh1[ot], al, cb, 0, 0, 0);
                c = __builtin_amdgcn_mfma_f32_16x16x32_bf16(bl1[ot], ah, c, 0, 0, 0);
                c = __builtin_amdgcn_mfma_f32_16x16x32_bf16(bh1[ot], ah, c, 0, 0, 0);
                *(f32x4*)(swv + row16 * 100 + ot * 16 + 4 * kq) = c;
            }
        }

        const int cg0 = cbit * 16 + hf * 8 + 2 * kq;   // global channel of spline A
        const f32x2 xf2 = (hf == 0) ? xf2_0 : xf2_1;

        // s-values (bias already in): 24 consecutive floats in swv row
        const float* sp = swv + row16 * 100 + 2 * kq * 12;
        float svA[12], svB[12];
#pragma unroll
        for (int e = 0; e < 4; ++e) {
            const f32x4 vA0 = *(const f32x4*)(sp);
            const f32x4 vA1 = *(const f32x4*)(sp + 4);
            const f32x4 vA2 = *(const f32x4*)(sp + 8);
            const f32x4 vB0 = *(const f32x4*)(sp + 12);
            const f32x4 vB1 = *(const f32x4*)(sp + 16);
            const f32x4 vB2 = *(const f32x4*)(sp + 20);
            svA[e]     = vA0[e];
            svA[e + 4] = vA1[e];
            svA[e + 8] = vA2[e];
            svB[e]     = vB0[e];
            svB[e + 4] = vB1[e];
            svB[e + 8] = vB2[e];
        }

        f32x2 y2;
        y2[0] = spline_horner(svA, xf2[0]);
        y2[1] = spline_horner(svB, xf2[1]);
        *(f32x2*)(out + (size_t)arow * 64 + 32 + cg0) = y2;
    }

    // ---- x1 passthrough at end: only even blocks (one copy per row group) ----
    if (cbit == 0) {
        for (int i = tid; i < 512; i += 256) {
            const int r = i >> 3, q = i & 7;               // 64 rows x 8 quads
            *(f32x4*)(out + (size_t)(block_row + r) * 64 + q * 4) =
                *(const f32x4*)(x + (size_t)(block_row + r) * 64 + q * 4);
        }
    }
}

// ---- fallback (R3 structure, known-pass): used only if ws is too small ----
__global__ __launch_bounds__(256) void bern_spline_fallback(
    const float* __restrict__ x, const float* __restrict__ W,
    const float* __restrict__ bias, float* __restrict__ out)
{
    __shared__ short Wh[12288];
    __shared__ short Wl[12288];
    __shared__ float bl[384];
    __shared__ float sl[4 * 16 * 100];

    const int tid  = threadIdx.x;
    const int wave = tid >> 6;
    const int lane = tid & 63;
    const int block_row = blockIdx.x * 64;

    for (int g = tid; g < 12288; g += 256) {
        const int o = g >> 5;
        const int k = g & 31;
        const float w = W[g];
        const short hi = f2bf(w);
        Wh[(k >> 3) * 3072 + o * 8 + (k & 7)] = hi;
        Wl[(k >> 3) * 3072 + o * 8 + (k & 7)] = f2bf(w - bf2f(hi));
    }
    for (int g = tid; g < 384; g += 256) bl[g] = bias[g];
    __syncthreads();

    for (int i = tid; i < 512; i += 256) {
        const int r = i >> 3, q = i & 7;
        *(f32x4*)(out + (size_t)(block_row + r) * 64 + q * 4) =
            *(const f32x4*)(x + (size_t)(block_row + r) * 64 + q * 4);
    }

    const int row16 = lane & 15;
    const int kq    = lane >> 4;
    const int arow  = block_row + wave * 16 + row16;
    const f32x4 a0 = *(const f32x4*)(x + (size_t)arow * 64 + kq * 8);
    const f32x4 a1 = *(const f32x4*)(x + (size_t)arow * 64 + kq * 8 + 4);
    v8s ah, al;
#pragma unroll
    for (int e = 0; e < 4; ++e) {
        const short h0 = f2bf(a0[e]);
        ah[e] = h0;     al[e] = f2bf(a0[e] - bf2f(h0));
        const short h1 = f2bf(a1[e]);
        ah[e + 4] = h1; al[e + 4] = f2bf(a1[e] - bf2f(h1));
    }

    float* swv = sl + wave * 1600;
    const f32x4 zero4 = {0.f, 0.f, 0.f, 0.f};

    for (int qt = 0; qt < 4; ++qt) {
        f32x4 acc[6];
#pragma unroll
        for (int ot = 0; ot < 6; ++ot) {
            const int otg = qt * 6 + ot;
            const int boff = kq * 3072 + (otg * 16 + row16) * 8;
            const v8s bh  = *(const v8s*)(Wh + boff);
            const v8s blo = *(const v8s*)(Wl + boff);
            f32x4 c = __builtin_amdgcn_mfma_f32_16x16x32_bf16(al, bh, zero4, 0, 0, 0);
            c = __builtin_amdgcn_mfma_f32_16x16x32_bf16(ah, blo, c, 0, 0, 0);
            acc[ot] = __builtin_amdgcn_mfma_f32_16x16x32_bf16(ah, bh, c, 0, 0, 0);
        }
#pragma unroll
        for (int ot = 0; ot < 6; ++ot)
#pragma unroll
            for (int r = 0; r < 4; ++r)
                swv[(kq * 4 + r) * 100 + ot * 16 + row16] = acc[ot][r];

#pragma unroll
        for (int p = 0; p < 2; ++p) {
            const int idx = p * 64 + lane;
            const int cl  = idx & 7;
            const int rr  = idx >> 3;
            const int cg  = qt * 8 + cl;

            const float* sp = swv + rr * 100 + cl * 12;
            const f32x4 s0 = *(const f32x4*)(sp);
            const f32x4 s1 = *(const f32x4*)(sp + 4);
            const f32x4 s2 = *(const f32x4*)(sp + 8);
            const f32x4 b0 = *(const f32x4*)(bl + cg * 12);
            const f32x4 b1 = *(const f32x4*)(bl + cg * 12 + 4);
            const f32x4 b2 = *(const f32x4*)(bl + cg * 12 + 8);

            float sv[12];
            sv[0]  = s0[0] + b0[0]; sv[1]  = s0[1] + b0[1];
            sv[2]  = s0[2] + b0[2]; sv[3]  = s0[3] + b0[3];
            sv[4]  = s1[0] + b1[0]; sv[5]  = s1[1] + b1[1];
            sv[6]  = s1[2] + b1[2]; sv[7]  = s1[3] + b1[3];
            sv[8]  = s2[0] + b2[0]; sv[9]  = s2[1] + b2[1];
            sv[10] = s2[2] + b2[2]; sv[11] = s2[3] + b2[3];

            const int rowg = block_row + wave * 16 + rr;
            const float xf = x[(size_t)rowg * 64 + 32 + cg];
            out[(size_t)rowg * 64 + 32 + cg] = spline_eval(sv, xf);
        }
    }
}

extern "C" void kernel_launch(void* const* d_in, const int* in_sizes, int n_in,
                              void* d_out, int out_size, void* d_ws, size_t ws_size,
                              hipStream_t stream) {
    const float* x = (const float*)d_in[0];
    const float* W = (const float*)d_in[1];
    const float* b = (const float*)d_in[2];
    float* out = (float*)d_out;

    if (d_ws != nullptr && ws_size >= 49152) {
        short* wsH = (short*)d_ws;
        short* wsL = wsH + 12288;
        prep_w<<<48, 256, 0, stream>>>(W, wsH, wsL);                     // 48 KB, L2-resident
        bern_spline_fast<<<2048, 256, 0, stream>>>(x, wsH, wsL, b, out); // 64 rows x 16 ch
    } else {
        bern_spline_fallback<<<1024, 256, 0, stream>>>(x, W, b, out);
    }
}

// Round 11
// 30.163 us; speedup vs baseline: 1.1442x; 1.1442x over previous
//
#include <hip/hip_runtime.h>

// BernsteinSplineCouplingBlock: BATCH=65536, CHANNELS=64, SPLIT1=SPLIT2=32, DEGREE=10
// out[:, :32] = x[:, :32]
// s = x1 @ W.T + b  -> [B*32, 12]; spline(s, x2) -> out[:, 32:]
// GEMM via split-bf16 (hi+lo) 3-MFMA chain for ~f32 precision.
// R11 = R8 + reg-passthrough + native exp2/log2. R10's truncation split REVERTED
//   (biased truncation errors accumulate linearly over K=32 -> 0.53 absmax fail;
//   RNE split is unbiased -> 0.0156. Lesson: rounding mode matters at K=32.)

typedef short v8s  __attribute__((ext_vector_type(8)));  // 8 x bf16 (4 VGPRs)
typedef float f32x4 __attribute__((ext_vector_type(4)));
typedef float f32x2 __attribute__((ext_vector_type(2)));

#define LOG2E 1.44269504088896340736f
#define LN2   0.69314718055994530942f

__device__ __forceinline__ short f2bf(float f) {
    union { float f; unsigned u; } v; v.f = f;
    return (short)((v.u + 0x7FFFu + ((v.u >> 16) & 1u)) >> 16);  // RNE
}

__device__ __forceinline__ float bf2f(short h) {
    union { unsigned u; float f; } v; v.u = ((unsigned)(unsigned short)h) << 16;
    return v.f;
}

__device__ __forceinline__ float sgn01(float x) {
    return (x > 0.f) ? 1.f : ((x < 0.f) ? -1.f : 0.f);
}

__device__ __forceinline__ float exp2_fast(float x) {
#if __has_builtin(__builtin_amdgcn_exp2f)
    return __builtin_amdgcn_exp2f(x);       // raw v_exp_f32 (2^x)
#else
    return exp2f(x);
#endif
}
__device__ __forceinline__ float log2_fast(float x) {
#if __has_builtin(__builtin_amdgcn_logf)
    return __builtin_amdgcn_logf(x);        // raw v_log_f32 (log2); args >= 1 here
#else
    return __log2f(x);
#endif
}

// log2-domain softplus: softplus(x)/ln2
__device__ __forceinline__ float softplus_l2(float x) {
    return log2_fast(1.0f + exp2_fast(x * LOG2E));
}

// Horner-Bernstein spline. sv[0..9] raw coeffs, sv[10] width, sv[11] height.
__device__ __forceinline__ float spline_horner(const float* sv, float xf) {
    // cumsum(softplus) in log2 units; ln2 cancels under inv-normalization.
    float spv[10], cn_[11];
    cn_[0] = 0.f;
    float run = 0.f;
#pragma unroll
    for (int j = 0; j < 10; ++j) {
        spv[j] = softplus_l2(sv[j]);
        run += spv[j];
        cn_[j + 1] = run;
    }
    const float inv = __fdividef(1.f, run);

    const float wd = fmaf(LN2, softplus_l2(sv[10]), 0.1f);  // softplus>0 => +0.1
    float hg = sv[11];
    hg += copysignf(0.1f, hg);

    const float t  = __fdividef(xf, wd) + 0.5f;
    const float tc = fminf(fmaxf(t, 0.f), 1.f);
    const float s  = 1.f - tc;

    // P = sum_{i=1..10} C10_i cn_[i] tc^i s^(10-i)   (value, unnormalized)
    // Q = sum_{i=0..9}  C9_i  spv[i] tc^i s^(9-i)    (deriv/10, unnormalized)
    const float C10[11] = {1.f,10.f,45.f,120.f,210.f,252.f,210.f,120.f,45.f,10.f,1.f};
    const float C9[10]  = {1.f,9.f,36.f,84.f,126.f,126.f,84.f,36.f,9.f,1.f};
    float tk = 1.f, P = 0.f, Q = 0.f;
#pragma unroll
    for (int i = 0; i < 10; ++i) {
        Q = fmaf(Q, s, tk * (C9[i] * spv[i]));
        P = fmaf(P, s, tk * (C10[i] * cn_[i]));   // i=0 term folds to 0
        tk *= tc;
    }
    P = fmaf(P, s, tk * cn_[10]);                 // i=10, C(10,10)=1

    const float der = 10.f * Q * inv;
    const float ym  = P * inv;
    float y = (t < 0.f) ? (t * der)
            : ((t > 1.f) ? fmaf(t - 1.f, der, 1.f) : ym);
    return (y - 0.5f) * hg;
}

// fallback math (R3-proven de Casteljau)
__device__ __forceinline__ float softplus_f(float x) {
    return __logf(1.0f + __expf(x));
}
__device__ __forceinline__ float spline_eval(const float* sv, float xf) {
    float cn[11];
    cn[0] = 0.f;
    float run = 0.f;
#pragma unroll
    for (int j = 0; j < 10; ++j) { run += softplus_f(sv[j]); cn[j + 1] = run; }
    const float inv = __fdividef(1.f, run);
    const float wd = softplus_f(sv[10]) + 0.1f;
    float hg = sv[11];
    hg += 0.1f * sgn01(hg);
    const float t   = __fdividef(xf, wd) + 0.5f;
    const float tc  = fminf(fmaxf(t, 0.f), 1.f);
#pragma unroll
    for (int n = 10; n >= 2; --n) {
#pragma unroll
        for (int i = 0; i < n; ++i) cn[i] += tc * (cn[i + 1] - cn[i]);
    }
    const float db    = cn[1] - cn[0];
    const float deriv = 10.f * db * inv;
    const float ym    = fmaf(tc, db, cn[0]) * inv;
    float y = (t < 0.f) ? (t * deriv)
            : ((t > 1.f) ? fmaf(t - 1.f, deriv, 1.f) : ym);
    return (y - 0.5f) * hg;
}

// ---- prep: split W f32 -> bf16 hi/lo (RNE both) in B-fragment order ----
// frag layout: [(k>>3)*3072 + out*8 + (k&7)], hi at wsH, lo at wsL
__global__ void prep_w(const float* __restrict__ W, short* __restrict__ wsH,
                       short* __restrict__ wsL) {
    const int g = blockIdx.x * 256 + threadIdx.x;
    if (g < 12288) {
        const int o = g >> 5;        // W row (out index 0..383)
        const int k = g & 31;
        const float w = W[g];
        const short hi = f2bf(w);
        const int off = (k >> 3) * 3072 + o * 8 + (k & 7);
        wsH[off] = hi;
        wsL[off] = f2bf(w - bf2f(hi));
    }
}

// ---- main: 2048 blocks = (row group) x (channel half), 4 waves, no barriers ----
__global__ __launch_bounds__(256) void bern_spline_fast(
    const float* __restrict__ x, const short* __restrict__ wsH,
    const short* __restrict__ wsL, const float* __restrict__ bias,
    float* __restrict__ out)
{
    __shared__ __align__(16) float sl[4 * 16 * 100];  // per-wave 16x(96+4pad), 25.6 KB

    const int tid  = threadIdx.x;
    const int wave = tid >> 6;
    const int lane = tid & 63;
    const int cbit = blockIdx.x & 1;            // channel half: ch in [cbit*16, +16)
    const int block_row = (blockIdx.x >> 1) * 64;

    const int row16 = lane & 15;
    const int kq    = lane >> 4;
    const int arow  = block_row + wave * 16 + row16;

    // xf pairs for both halves — issued first, consumed deep in spline phase
    const int cg0_h0 = cbit * 16 + 2 * kq;
    const f32x2 xf2_0 = *(const f32x2*)(x + (size_t)arow * 64 + 32 + cg0_h0);
    const f32x2 xf2_1 = *(const f32x2*)(x + (size_t)arow * 64 + 32 + cg0_h0 + 8);

    // A fragment: lane holds x1[row = l&15][k = (l>>4)*8 .. +7], RNE hi+lo split
    const f32x4 a0 = *(const f32x4*)(x + (size_t)arow * 64 + kq * 8);
    const f32x4 a1 = *(const f32x4*)(x + (size_t)arow * 64 + kq * 8 + 4);
    v8s ah, al;
#pragma unroll
    for (int e = 0; e < 4; ++e) {
        const short h0 = f2bf(a0[e]);
        ah[e] = h0;     al[e] = f2bf(a0[e] - bf2f(h0));
        const short h1 = f2bf(a1[e]);
        ah[e + 4] = h1; al[e + 4] = f2bf(a1[e] - bf2f(h1));
    }

    // ---- x1 passthrough directly from A-fragment registers (even blocks) ----
    if (cbit == 0) {
        *(f32x4*)(out + (size_t)arow * 64 + kq * 8)     = a0;
        *(f32x4*)(out + (size_t)arow * 64 + kq * 8 + 4) = a1;
    }

    // bias per C tile: constant along batch-row dim -> MFMA C-in {bv,bv,bv,bv}
    float bv0[6], bv1[6];
#pragma unroll
    for (int ot = 0; ot < 6; ++ot) {
        bv0[ot] = bias[(cbit * 12 + ot) * 16 + row16];
        bv1[ot] = bias[(cbit * 12 + 6 + ot) * 16 + row16];
    }

    float* swv = sl + wave * 1600;   // wave-private transpose buffer

    // ---- B-frag loads half 0 ----
    v8s bh0[6], bl0[6];
#pragma unroll
    for (int ot = 0; ot < 6; ++ot) {
        const int boff = kq * 3072 + ((cbit * 12 + ot) * 16 + row16) * 8;
        bh0[ot] = *(const v8s*)(wsH + boff);
        bl0[ot] = *(const v8s*)(wsL + boff);
    }

    // ---- MFMA half 0 (bias in C) + LDS scatter ----
#pragma unroll
    for (int ot = 0; ot < 6; ++ot) {
        f32x4 cb; cb[0] = bv0[ot]; cb[1] = bv0[ot]; cb[2] = bv0[ot]; cb[3] = bv0[ot];
        f32x4 c = __builtin_amdgcn_mfma_f32_16x16x32_bf16(al, bh0[ot], cb, 0, 0, 0);
        c = __builtin_amdgcn_mfma_f32_16x16x32_bf16(ah, bl0[ot], c, 0, 0, 0);
        c = __builtin_amdgcn_mfma_f32_16x16x32_bf16(ah, bh0[ot], c, 0, 0, 0);
#pragma unroll
        for (int r = 0; r < 4; ++r)
            swv[(kq * 4 + r) * 100 + ot * 16 + row16] = c[r];
    }

    // ---- PREFETCH: B-frag loads half 1 (in flight during half-0 splines) ----
    v8s bh1[6], bl1[6];
#pragma unroll
    for (int ot = 0; ot < 6; ++ot) {
        const int boff = kq * 3072 + ((cbit * 12 + 6 + ot) * 16 + row16) * 8;
        bh1[ot] = *(const v8s*)(wsH + boff);
        bl1[ot] = *(const v8s*)(wsL + boff);
    }

    // ---- splines: lane = (row16, channel pair 2*kq, 2*kq+1) per half ----
#pragma unroll
    for (int hf = 0; hf < 2; ++hf) {
        if (hf == 1) {
            // MFMA half 1 (bias in C) + LDS scatter (prefetched B-frags)
#pragma unroll
            for (int ot = 0; ot < 6; ++ot) {
                f32x4 cb; cb[0] = bv1[ot]; cb[1] = bv1[ot]; cb[2] = bv1[ot]; cb[3] = bv1[ot];
                f32x4 c = __builtin_amdgcn_mfma_f32_16x16x32_bf16(al, bh1[ot], cb, 0, 0, 0);
                c = __builtin_amdgcn_mfma_f32_16x16x32_bf16(ah, bl1[ot], c, 0, 0, 0);
                c = __builtin_amdgcn_mfma_f32_16x16x32_bf16(ah, bh1[ot], c, 0, 0, 0);
#pragma unroll
                for (int r = 0; r < 4; ++r)
                    swv[(kq * 4 + r) * 100 + ot * 16 + row16] = c[r];
            }
        }

        const int cg0 = cbit * 16 + hf * 8 + 2 * kq;   // global channel of spline A
        const f32x2 xf2 = (hf == 0) ? xf2_0 : xf2_1;

        // s-values (bias already in): 24 consecutive floats in swv row
        const float* sp = swv + row16 * 100 + 2 * kq * 12;
        const f32x4 vA0 = *(const f32x4*)(sp);
        const f32x4 vA1 = *(const f32x4*)(sp + 4);
        const f32x4 vA2 = *(const f32x4*)(sp + 8);
        const f32x4 vB0 = *(const f32x4*)(sp + 12);
        const f32x4 vB1 = *(const f32x4*)(sp + 16);
        const f32x4 vB2 = *(const f32x4*)(sp + 20);

        float svA[12], svB[12];
#pragma unroll
        for (int e = 0; e < 4; ++e) {
            svA[e]     = vA0[e];
            svA[e + 4] = vA1[e];
            svA[e + 8] = vA2[e];
            svB[e]     = vB0[e];
            svB[e + 4] = vB1[e];
            svB[e + 8] = vB2[e];
        }

        f32x2 y2;
        y2[0] = spline_horner(svA, xf2[0]);
        y2[1] = spline_horner(svB, xf2[1]);
        *(f32x2*)(out + (size_t)arow * 64 + 32 + cg0) = y2;
    }
}

// ---- fallback (R3 structure, known-pass): used only if ws is too small ----
__global__ __launch_bounds__(256) void bern_spline_fallback(
    const float* __restrict__ x, const float* __restrict__ W,
    const float* __restrict__ bias, float* __restrict__ out)
{
    __shared__ short Wh[12288];
    __shared__ short Wl[12288];
    __shared__ float bl[384];
    __shared__ float sl[4 * 16 * 100];

    const int tid  = threadIdx.x;
    const int wave = tid >> 6;
    const int lane = tid & 63;
    const int block_row = blockIdx.x * 64;

    for (int g = tid; g < 12288; g += 256) {
        const int o = g >> 5;
        const int k = g & 31;
        const float w = W[g];
        const short hi = f2bf(w);
        Wh[(k >> 3) * 3072 + o * 8 + (k & 7)] = hi;
        Wl[(k >> 3) * 3072 + o * 8 + (k & 7)] = f2bf(w - bf2f(hi));
    }
    for (int g = tid; g < 384; g += 256) bl[g] = bias[g];
    __syncthreads();

    for (int i = tid; i < 512; i += 256) {
        const int r = i >> 3, q = i & 7;
        *(f32x4*)(out + (size_t)(block_row + r) * 64 + q * 4) =
            *(const f32x4*)(x + (size_t)(block_row + r) * 64 + q * 4);
    }

    const int row16 = lane & 15;
    const int kq    = lane >> 4;
    const int arow  = block_row + wave * 16 + row16;
    const f32x4 a0 = *(const f32x4*)(x + (size_t)arow * 64 + kq * 8);
    const f32x4 a1 = *(const f32x4*)(x + (size_t)arow * 64 + kq * 8 + 4);
    v8s ah, al;
#pragma unroll
    for (int e = 0; e < 4; ++e) {
        const short h0 = f2bf(a0[e]);
        ah[e] = h0;     al[e] = f2bf(a0[e] - bf2f(h0));
        const short h1 = f2bf(a1[e]);
        ah[e + 4] = h1; al[e + 4] = f2bf(a1[e] - bf2f(h1));
    }

    float* swv = sl + wave * 1600;
    const f32x4 zero4 = {0.f, 0.f, 0.f, 0.f};

    for (int qt = 0; qt < 4; ++qt) {
        f32x4 acc[6];
#pragma unroll
        for (int ot = 0; ot < 6; ++ot) {
            const int otg = qt * 6 + ot;
            const int boff = kq * 3072 + (otg * 16 + row16) * 8;
            const v8s bh  = *(const v8s*)(Wh + boff);
            const v8s blo = *(const v8s*)(Wl + boff);
            f32x4 c = __builtin_amdgcn_mfma_f32_16x16x32_bf16(al, bh, zero4, 0, 0, 0);
            c = __builtin_amdgcn_mfma_f32_16x16x32_bf16(ah, blo, c, 0, 0, 0);
            acc[ot] = __builtin_amdgcn_mfma_f32_16x16x32_bf16(ah, bh, c, 0, 0, 0);
        }
#pragma unroll
        for (int ot = 0; ot < 6; ++ot)
#pragma unroll
            for (int r = 0; r < 4; ++r)
                swv[(kq * 4 + r) * 100 + ot * 16 + row16] = acc[ot][r];

#pragma unroll
        for (int p = 0; p < 2; ++p) {
            const int idx = p * 64 + lane;
            const int cl  = idx & 7;
            const int rr  = idx >> 3;
            const int cg  = qt * 8 + cl;

            const float* sp = swv + rr * 100 + cl * 12;
            const f32x4 s0 = *(const f32x4*)(sp);
            const f32x4 s1 = *(const f32x4*)(sp + 4);
            const f32x4 s2 = *(const f32x4*)(sp + 8);
            const f32x4 b0 = *(const f32x4*)(bl + cg * 12);
            const f32x4 b1 = *(const f32x4*)(bl + cg * 12 + 4);
            const f32x4 b2 = *(const f32x4*)(bl + cg * 12 + 8);

            float sv[12];
            sv[0]  = s0[0] + b0[0]; sv[1]  = s0[1] + b0[1];
            sv[2]  = s0[2] + b0[2]; sv[3]  = s0[3] + b0[3];
            sv[4]  = s1[0] + b1[0]; sv[5]  = s1[1] + b1[1];
            sv[6]  = s1[2] + b1[2]; sv[7]  = s1[3] + b1[3];
            sv[8]  = s2[0] + b2[0]; sv[9]  = s2[1] + b2[1];
            sv[10] = s2[2] + b2[2]; sv[11] = s2[3] + b2[3];

            const int rowg = block_row + wave * 16 + rr;
            const float xf = x[(size_t)rowg * 64 + 32 + cg];
            out[(size_t)rowg * 64 + 32 + cg] = spline_eval(sv, xf);
        }
    }
}

extern "C" void kernel_launch(void* const* d_in, const int* in_sizes, int n_in,
                              void* d_out, int out_size, void* d_ws, size_t ws_size,
                              hipStream_t stream) {
    const float* x = (const float*)d_in[0];
    const float* W = (const float*)d_in[1];
    const float* b = (const float*)d_in[2];
    float* out = (float*)d_out;

    if (d_ws != nullptr && ws_size >= 49152) {
        short* wsH = (short*)d_ws;
        short* wsL = wsH + 12288;
        prep_w<<<48, 256, 0, stream>>>(W, wsH, wsL);                     // 48 KB, L2-resident
        bern_spline_fast<<<2048, 256, 0, stream>>>(x, wsH, wsL, b, out); // 64 rows x 16 ch
    } else {
        bern_spline_fallback<<<1024, 256, 0, stream>>>(x, W, b, out);
    }
}

// Round 12
// 29.562 us; speedup vs baseline: 1.1675x; 1.0203x over previous
//
#include <hip/hip_runtime.h>

// BernsteinSplineCouplingBlock: BATCH=65536, CHANNELS=64, SPLIT1=SPLIT2=32, DEGREE=10
// out[:, :32] = x[:, :32]
// s = x1 @ W.T + b  -> [B*32, 12]; spline(s, x2) -> out[:, 32:]
// GEMM via split-bf16 (hi+lo) 3-MFMA chain for ~f32 precision.
// R12 = R11 + pipeline restructure: both B-frag halves loaded up front; MFMA1
//   computed into registers BEFORE spline0 (aliasing hazard broken by reading
//   sv0 into regs first); sv1 LDS reads issued before spline0 compute so their
//   latency hides under ~800 cycles of spline VALU.

typedef short v8s  __attribute__((ext_vector_type(8)));  // 8 x bf16 (4 VGPRs)
typedef float f32x4 __attribute__((ext_vector_type(4)));
typedef float f32x2 __attribute__((ext_vector_type(2)));

#define LOG2E 1.44269504088896340736f
#define LN2   0.69314718055994530942f

__device__ __forceinline__ short f2bf(float f) {
    union { float f; unsigned u; } v; v.f = f;
    return (short)((v.u + 0x7FFFu + ((v.u >> 16) & 1u)) >> 16);  // RNE
}

__device__ __forceinline__ float bf2f(short h) {
    union { unsigned u; float f; } v; v.u = ((unsigned)(unsigned short)h) << 16;
    return v.f;
}

__device__ __forceinline__ float sgn01(float x) {
    return (x > 0.f) ? 1.f : ((x < 0.f) ? -1.f : 0.f);
}

__device__ __forceinline__ float exp2_fast(float x) {
#if __has_builtin(__builtin_amdgcn_exp2f)
    return __builtin_amdgcn_exp2f(x);       // raw v_exp_f32 (2^x)
#else
    return exp2f(x);
#endif
}
__device__ __forceinline__ float log2_fast(float x) {
#if __has_builtin(__builtin_amdgcn_logf)
    return __builtin_amdgcn_logf(x);        // raw v_log_f32 (log2); args >= 1 here
#else
    return __log2f(x);
#endif
}

// log2-domain softplus: softplus(x)/ln2
__device__ __forceinline__ float softplus_l2(float x) {
    return log2_fast(1.0f + exp2_fast(x * LOG2E));
}

// Horner-Bernstein spline. sv[0..9] raw coeffs, sv[10] width, sv[11] height.
__device__ __forceinline__ float spline_horner(const float* sv, float xf) {
    // cumsum(softplus) in log2 units; ln2 cancels under inv-normalization.
    float spv[10], cn_[11];
    cn_[0] = 0.f;
    float run = 0.f;
#pragma unroll
    for (int j = 0; j < 10; ++j) {
        spv[j] = softplus_l2(sv[j]);
        run += spv[j];
        cn_[j + 1] = run;
    }
    const float inv = __fdividef(1.f, run);

    const float wd = fmaf(LN2, softplus_l2(sv[10]), 0.1f);  // softplus>0 => +0.1
    float hg = sv[11];
    hg += copysignf(0.1f, hg);

    const float t  = __fdividef(xf, wd) + 0.5f;
    const float tc = fminf(fmaxf(t, 0.f), 1.f);
    const float s  = 1.f - tc;

    // P = sum_{i=1..10} C10_i cn_[i] tc^i s^(10-i)   (value, unnormalized)
    // Q = sum_{i=0..9}  C9_i  spv[i] tc^i s^(9-i)    (deriv/10, unnormalized)
    const float C10[11] = {1.f,10.f,45.f,120.f,210.f,252.f,210.f,120.f,45.f,10.f,1.f};
    const float C9[10]  = {1.f,9.f,36.f,84.f,126.f,126.f,84.f,36.f,9.f,1.f};
    float tk = 1.f, P = 0.f, Q = 0.f;
#pragma unroll
    for (int i = 0; i < 10; ++i) {
        Q = fmaf(Q, s, tk * (C9[i] * spv[i]));
        P = fmaf(P, s, tk * (C10[i] * cn_[i]));   // i=0 term folds to 0
        tk *= tc;
    }
    P = fmaf(P, s, tk * cn_[10]);                 // i=10, C(10,10)=1

    const float der = 10.f * Q * inv;
    const float ym  = P * inv;
    float y = (t < 0.f) ? (t * der)
            : ((t > 1.f) ? fmaf(t - 1.f, der, 1.f) : ym);
    return (y - 0.5f) * hg;
}

// fallback math (R3-proven de Casteljau)
__device__ __forceinline__ float softplus_f(float x) {
    return __logf(1.0f + __expf(x));
}
__device__ __forceinline__ float spline_eval(const float* sv, float xf) {
    float cn[11];
    cn[0] = 0.f;
    float run = 0.f;
#pragma unroll
    for (int j = 0; j < 10; ++j) { run += softplus_f(sv[j]); cn[j + 1] = run; }
    const float inv = __fdividef(1.f, run);
    const float wd = softplus_f(sv[10]) + 0.1f;
    float hg = sv[11];
    hg += 0.1f * sgn01(hg);
    const float t   = __fdividef(xf, wd) + 0.5f;
    const float tc  = fminf(fmaxf(t, 0.f), 1.f);
#pragma unroll
    for (int n = 10; n >= 2; --n) {
#pragma unroll
        for (int i = 0; i < n; ++i) cn[i] += tc * (cn[i + 1] - cn[i]);
    }
    const float db    = cn[1] - cn[0];
    const float deriv = 10.f * db * inv;
    const float ym    = fmaf(tc, db, cn[0]) * inv;
    float y = (t < 0.f) ? (t * deriv)
            : ((t > 1.f) ? fmaf(t - 1.f, deriv, 1.f) : ym);
    return (y - 0.5f) * hg;
}

// ---- prep: split W f32 -> bf16 hi/lo (RNE both) in B-fragment order ----
// frag layout: [(k>>3)*3072 + out*8 + (k&7)], hi at wsH, lo at wsL
__global__ void prep_w(const float* __restrict__ W, short* __restrict__ wsH,
                       short* __restrict__ wsL) {
    const int g = blockIdx.x * 256 + threadIdx.x;
    if (g < 12288) {
        const int o = g >> 5;        // W row (out index 0..383)
        const int k = g & 31;
        const float w = W[g];
        const short hi = f2bf(w);
        const int off = (k >> 3) * 3072 + o * 8 + (k & 7);
        wsH[off] = hi;
        wsL[off] = f2bf(w - bf2f(hi));
    }
}

// ---- main: 2048 blocks = (row group) x (channel half), 4 waves, no barriers ----
__global__ __launch_bounds__(256) void bern_spline_fast(
    const float* __restrict__ x, const short* __restrict__ wsH,
    const short* __restrict__ wsL, const float* __restrict__ bias,
    float* __restrict__ out)
{
    __shared__ __align__(16) float sl[4 * 16 * 100];  // per-wave 16x(96+4pad), 25.6 KB

    const int tid  = threadIdx.x;
    const int wave = tid >> 6;
    const int lane = tid & 63;
    const int cbit = blockIdx.x & 1;            // channel half: ch in [cbit*16, +16)
    const int block_row = (blockIdx.x >> 1) * 64;

    const int row16 = lane & 15;
    const int kq    = lane >> 4;
    const int arow  = block_row + wave * 16 + row16;

    // xf pairs for both halves — issued first, consumed deep in spline phase
    const int cg0_h0 = cbit * 16 + 2 * kq;
    const f32x2 xf2_0 = *(const f32x2*)(x + (size_t)arow * 64 + 32 + cg0_h0);
    const f32x2 xf2_1 = *(const f32x2*)(x + (size_t)arow * 64 + 32 + cg0_h0 + 8);

    // A fragment: lane holds x1[row = l&15][k = (l>>4)*8 .. +7], RNE hi+lo split
    const f32x4 a0 = *(const f32x4*)(x + (size_t)arow * 64 + kq * 8);
    const f32x4 a1 = *(const f32x4*)(x + (size_t)arow * 64 + kq * 8 + 4);
    v8s ah, al;
#pragma unroll
    for (int e = 0; e < 4; ++e) {
        const short h0 = f2bf(a0[e]);
        ah[e] = h0;     al[e] = f2bf(a0[e] - bf2f(h0));
        const short h1 = f2bf(a1[e]);
        ah[e + 4] = h1; al[e + 4] = f2bf(a1[e] - bf2f(h1));
    }

    // ---- x1 passthrough directly from A-fragment registers (even blocks) ----
    if (cbit == 0) {
        *(f32x4*)(out + (size_t)arow * 64 + kq * 8)     = a0;
        *(f32x4*)(out + (size_t)arow * 64 + kq * 8 + 4) = a1;
    }

    // bias per C tile: constant along batch-row dim -> MFMA C-in {bv,bv,bv,bv}
    float bv0[6], bv1[6];
#pragma unroll
    for (int ot = 0; ot < 6; ++ot) {
        bv0[ot] = bias[(cbit * 12 + ot) * 16 + row16];
        bv1[ot] = bias[(cbit * 12 + 6 + ot) * 16 + row16];
    }

    float* swv = sl + wave * 1600;   // wave-private transpose buffer

    // ---- B-frag loads, BOTH halves up front (L2 latency overlapped) ----
    v8s bh0[6], bl0[6], bh1[6], bl1[6];
#pragma unroll
    for (int ot = 0; ot < 6; ++ot) {
        const int boff0 = kq * 3072 + ((cbit * 12 + ot) * 16 + row16) * 8;
        const int boff1 = kq * 3072 + ((cbit * 12 + 6 + ot) * 16 + row16) * 8;
        bh0[ot] = *(const v8s*)(wsH + boff0);
        bl0[ot] = *(const v8s*)(wsL + boff0);
        bh1[ot] = *(const v8s*)(wsH + boff1);
        bl1[ot] = *(const v8s*)(wsL + boff1);
    }

    // ---- MFMA half 0 (bias in C) + LDS scatter ----
#pragma unroll
    for (int ot = 0; ot < 6; ++ot) {
        f32x4 cb; cb[0] = bv0[ot]; cb[1] = bv0[ot]; cb[2] = bv0[ot]; cb[3] = bv0[ot];
        f32x4 c = __builtin_amdgcn_mfma_f32_16x16x32_bf16(al, bh0[ot], cb, 0, 0, 0);
        c = __builtin_amdgcn_mfma_f32_16x16x32_bf16(ah, bl0[ot], c, 0, 0, 0);
        c = __builtin_amdgcn_mfma_f32_16x16x32_bf16(ah, bh0[ot], c, 0, 0, 0);
#pragma unroll
        for (int r = 0; r < 4; ++r)
            swv[(kq * 4 + r) * 100 + ot * 16 + row16] = c[r];
    }

    // ---- read sv0 into registers (the one exposed LDS round trip) ----
    const float* sp = swv + row16 * 100 + 2 * kq * 12;
    const f32x4 vA00 = *(const f32x4*)(sp);
    const f32x4 vA01 = *(const f32x4*)(sp + 4);
    const f32x4 vA02 = *(const f32x4*)(sp + 8);
    const f32x4 vB00 = *(const f32x4*)(sp + 12);
    const f32x4 vB01 = *(const f32x4*)(sp + 16);
    const f32x4 vB02 = *(const f32x4*)(sp + 20);

    // ---- MFMA half 1 into registers (no LDS touch -> legal before spline0) ----
    f32x4 c10, c11, c12, c13, c14, c15;
    {
        f32x4 cb;
#define MFMA_H1(CC, OT) \
        cb[0] = bv1[OT]; cb[1] = bv1[OT]; cb[2] = bv1[OT]; cb[3] = bv1[OT]; \
        CC = __builtin_amdgcn_mfma_f32_16x16x32_bf16(al, bh1[OT], cb, 0, 0, 0); \
        CC = __builtin_amdgcn_mfma_f32_16x16x32_bf16(ah, bl1[OT], CC, 0, 0, 0); \
        CC = __builtin_amdgcn_mfma_f32_16x16x32_bf16(ah, bh1[OT], CC, 0, 0, 0);
        MFMA_H1(c10, 0) MFMA_H1(c11, 1) MFMA_H1(c12, 2)
        MFMA_H1(c13, 3) MFMA_H1(c14, 4) MFMA_H1(c15, 5)
#undef MFMA_H1
    }

    // ---- write1 (after sv0 is safely in regs) ----
#pragma unroll
    for (int r = 0; r < 4; ++r) {
        swv[(kq * 4 + r) * 100 +  0 + row16] = c10[r];
        swv[(kq * 4 + r) * 100 + 16 + row16] = c11[r];
        swv[(kq * 4 + r) * 100 + 32 + row16] = c12[r];
        swv[(kq * 4 + r) * 100 + 48 + row16] = c13[r];
        swv[(kq * 4 + r) * 100 + 64 + row16] = c14[r];
        swv[(kq * 4 + r) * 100 + 80 + row16] = c15[r];
    }

    // ---- issue sv1 reads NOW; latency hides under spline0's VALU chain ----
    const f32x4 vA10 = *(const f32x4*)(sp);
    const f32x4 vA11 = *(const f32x4*)(sp + 4);
    const f32x4 vA12 = *(const f32x4*)(sp + 8);
    const f32x4 vB10 = *(const f32x4*)(sp + 12);
    const f32x4 vB11 = *(const f32x4*)(sp + 16);
    const f32x4 vB12 = *(const f32x4*)(sp + 20);

    // ---- spline half 0 ----
    {
        float svA[12], svB[12];
#pragma unroll
        for (int e = 0; e < 4; ++e) {
            svA[e] = vA00[e]; svA[e + 4] = vA01[e]; svA[e + 8] = vA02[e];
            svB[e] = vB00[e]; svB[e + 4] = vB01[e]; svB[e + 8] = vB02[e];
        }
        f32x2 y2;
        y2[0] = spline_horner(svA, xf2_0[0]);
        y2[1] = spline_horner(svB, xf2_0[1]);
        *(f32x2*)(out + (size_t)arow * 64 + 32 + cg0_h0) = y2;
    }

    // ---- spline half 1 ----
    {
        float svA[12], svB[12];
#pragma unroll
        for (int e = 0; e < 4; ++e) {
            svA[e] = vA10[e]; svA[e + 4] = vA11[e]; svA[e + 8] = vA12[e];
            svB[e] = vB10[e]; svB[e + 4] = vB11[e]; svB[e + 8] = vB12[e];
        }
        f32x2 y2;
        y2[0] = spline_horner(svA, xf2_1[0]);
        y2[1] = spline_horner(svB, xf2_1[1]);
        *(f32x2*)(out + (size_t)arow * 64 + 32 + cg0_h0 + 8) = y2;
    }
}

// ---- fallback (R3 structure, known-pass): used only if ws is too small ----
__global__ __launch_bounds__(256) void bern_spline_fallback(
    const float* __restrict__ x, const float* __restrict__ W,
    const float* __restrict__ bias, float* __restrict__ out)
{
    __shared__ short Wh[12288];
    __shared__ short Wl[12288];
    __shared__ float bl[384];
    __shared__ float sl[4 * 16 * 100];

    const int tid  = threadIdx.x;
    const int wave = tid >> 6;
    const int lane = tid & 63;
    const int block_row = blockIdx.x * 64;

    for (int g = tid; g < 12288; g += 256) {
        const int o = g >> 5;
        const int k = g & 31;
        const float w = W[g];
        const short hi = f2bf(w);
        Wh[(k >> 3) * 3072 + o * 8 + (k & 7)] = hi;
        Wl[(k >> 3) * 3072 + o * 8 + (k & 7)] = f2bf(w - bf2f(hi));
    }
    for (int g = tid; g < 384; g += 256) bl[g] = bias[g];
    __syncthreads();

    for (int i = tid; i < 512; i += 256) {
        const int r = i >> 3, q = i & 7;
        *(f32x4*)(out + (size_t)(block_row + r) * 64 + q * 4) =
            *(const f32x4*)(x + (size_t)(block_row + r) * 64 + q * 4);
    }

    const int row16 = lane & 15;
    const int kq    = lane >> 4;
    const int arow  = block_row + wave * 16 + row16;
    const f32x4 a0 = *(const f32x4*)(x + (size_t)arow * 64 + kq * 8);
    const f32x4 a1 = *(const f32x4*)(x + (size_t)arow * 64 + kq * 8 + 4);
    v8s ah, al;
#pragma unroll
    for (int e = 0; e < 4; ++e) {
        const short h0 = f2bf(a0[e]);
        ah[e] = h0;     al[e] = f2bf(a0[e] - bf2f(h0));
        const short h1 = f2bf(a1[e]);
        ah[e + 4] = h1; al[e + 4] = f2bf(a1[e] - bf2f(h1));
    }

    float* swv = sl + wave * 1600;
    const f32x4 zero4 = {0.f, 0.f, 0.f, 0.f};

    for (int qt = 0; qt < 4; ++qt) {
        f32x4 acc[6];
#pragma unroll
        for (int ot = 0; ot < 6; ++ot) {
            const int otg = qt * 6 + ot;
            const int boff = kq * 3072 + (otg * 16 + row16) * 8;
            const v8s bh  = *(const v8s*)(Wh + boff);
            const v8s blo = *(const v8s*)(Wl + boff);
            f32x4 c = __builtin_amdgcn_mfma_f32_16x16x32_bf16(al, bh, zero4, 0, 0, 0);
            c = __builtin_amdgcn_mfma_f32_16x16x32_bf16(ah, blo, c, 0, 0, 0);
            acc[ot] = __builtin_amdgcn_mfma_f32_16x16x32_bf16(ah, bh, c, 0, 0, 0);
        }
#pragma unroll
        for (int ot = 0; ot < 6; ++ot)
#pragma unroll
            for (int r = 0; r < 4; ++r)
                swv[(kq * 4 + r) * 100 + ot * 16 + row16] = acc[ot][r];

#pragma unroll
        for (int p = 0; p < 2; ++p) {
            const int idx = p * 64 + lane;
            const int cl  = idx & 7;
            const int rr  = idx >> 3;
            const int cg  = qt * 8 + cl;

            const float* sp = swv + rr * 100 + cl * 12;
            const f32x4 s0 = *(const f32x4*)(sp);
            const f32x4 s1 = *(const f32x4*)(sp + 4);
            const f32x4 s2 = *(const f32x4*)(sp + 8);
            const f32x4 b0 = *(const f32x4*)(bl + cg * 12);
            const f32x4 b1 = *(const f32x4*)(bl + cg * 12 + 4);
            const f32x4 b2 = *(const f32x4*)(bl + cg * 12 + 8);

            float sv[12];
            sv[0]  = s0[0] + b0[0]; sv[1]  = s0[1] + b0[1];
            sv[2]  = s0[2] + b0[2]; sv[3]  = s0[3] + b0[3];
            sv[4]  = s1[0] + b1[0]; sv[5]  = s1[1] + b1[1];
            sv[6]  = s1[2] + b1[2]; sv[7]  = s1[3] + b1[3];
            sv[8]  = s2[0] + b2[0]; sv[9]  = s2[1] + b2[1];
            sv[10] = s2[2] + b2[2]; sv[11] = s2[3] + b2[3];

            const int rowg = block_row + wave * 16 + rr;
            const float xf = x[(size_t)rowg * 64 + 32 + cg];
            out[(size_t)rowg * 64 + 32 + cg] = spline_eval(sv, xf);
        }
    }
}

extern "C" void kernel_launch(void* const* d_in, const int* in_sizes, int n_in,
                              void* d_out, int out_size, void* d_ws, size_t ws_size,
                              hipStream_t stream) {
    const float* x = (const float*)d_in[0];
    const float* W = (const float*)d_in[1];
    const float* b = (const float*)d_in[2];
    float* out = (float*)d_out;

    if (d_ws != nullptr && ws_size >= 49152) {
        short* wsH = (short*)d_ws;
        short* wsL = wsH + 12288;
        prep_w<<<48, 256, 0, stream>>>(W, wsH, wsL);                     // 48 KB, L2-resident
        bern_spline_fast<<<2048, 256, 0, stream>>>(x, wsH, wsL, b, out); // 64 rows x 16 ch
    } else {
        bern_spline_fallback<<<1024, 256, 0, stream>>>(x, W, b, out);
    }
}

// Round 13
// 28.425 us; speedup vs baseline: 1.2142x; 1.0400x over previous
//
#include <hip/hip_runtime.h>

// BernsteinSplineCouplingBlock: BATCH=65536, CHANNELS=64, SPLIT1=SPLIT2=32, DEGREE=10
// out[:, :32] = x[:, :32]
// s = x1 @ W.T + b  -> [B*32, 12]; spline(s, x2) -> out[:, 32:]
// GEMM via split-bf16 (hi+lo) 3-MFMA chain for ~f32 precision.
// R13 = R12 + packed-f32 spline: both splines of a lane's (A,B) pair evaluated
//   as f32x2 vector math -> v_pk_fma_f32/v_pk_mul_f32 (2 f32 per issue slot).
//   Trans (exp/log/rcp) remain scalar per element; tail selects per element.

typedef short v8s  __attribute__((ext_vector_type(8)));  // 8 x bf16 (4 VGPRs)
typedef float f32x4 __attribute__((ext_vector_type(4)));
typedef float f32x2 __attribute__((ext_vector_type(2)));

#define LOG2E 1.44269504088896340736f
#define LN2   0.69314718055994530942f

__device__ __forceinline__ short f2bf(float f) {
    union { float f; unsigned u; } v; v.f = f;
    return (short)((v.u + 0x7FFFu + ((v.u >> 16) & 1u)) >> 16);  // RNE
}

__device__ __forceinline__ float bf2f(short h) {
    union { unsigned u; float f; } v; v.u = ((unsigned)(unsigned short)h) << 16;
    return v.f;
}

__device__ __forceinline__ float sgn01(float x) {
    return (x > 0.f) ? 1.f : ((x < 0.f) ? -1.f : 0.f);
}

__device__ __forceinline__ float exp2_fast(float x) {
#if __has_builtin(__builtin_amdgcn_exp2f)
    return __builtin_amdgcn_exp2f(x);       // raw v_exp_f32 (2^x)
#else
    return exp2f(x);
#endif
}
__device__ __forceinline__ float log2_fast(float x) {
#if __has_builtin(__builtin_amdgcn_logf)
    return __builtin_amdgcn_logf(x);        // raw v_log_f32 (log2); args >= 1 here
#else
    return __log2f(x);
#endif
}

// ---- packed-pair spline: sv[0..9] raw coeffs, sv[10] width, sv[11] height ----
// Per-component math identical (same op order) to the scalar R12 version.
__device__ __forceinline__ f32x2 spline_horner2(const f32x2* sv, f32x2 xf) {
    const f32x2 zero = {0.f, 0.f};
    const f32x2 one  = {1.f, 1.f};

    f32x2 spv[10], cn_[11];
    cn_[0] = zero;
    f32x2 run = zero;
#pragma unroll
    for (int j = 0; j < 10; ++j) {
        const f32x2 xs = sv[j] * LOG2E;        // v_pk_mul
        f32x2 e;
        e[0] = exp2_fast(xs[0]);
        e[1] = exp2_fast(xs[1]);
        const f32x2 oe = e + 1.0f;             // v_pk_add
        f32x2 l;
        l[0] = log2_fast(oe[0]);
        l[1] = log2_fast(oe[1]);
        spv[j] = l;
        run = run + l;                          // v_pk_add (cumsum)
        cn_[j + 1] = run;
    }
    f32x2 inv;
    inv[0] = __fdividef(1.f, run[0]);
    inv[1] = __fdividef(1.f, run[1]);

    // width: wd = ln2*softplus_l2 + 0.1 (softplus>0 => +0.1)
    const f32x2 xsw = sv[10] * LOG2E;
    f32x2 ew;
    ew[0] = exp2_fast(xsw[0]);
    ew[1] = exp2_fast(xsw[1]);
    const f32x2 oew = ew + 1.0f;
    f32x2 lw;
    lw[0] = log2_fast(oew[0]);
    lw[1] = log2_fast(oew[1]);
    const f32x2 ln2v = {LN2, LN2};
    const f32x2 p1v  = {0.1f, 0.1f};
    const f32x2 wd = __builtin_elementwise_fma(ln2v, lw, p1v);

    f32x2 hg = sv[11];
    hg[0] += copysignf(0.1f, hg[0]);
    hg[1] += copysignf(0.1f, hg[1]);

    f32x2 tq;
    tq[0] = __fdividef(xf[0], wd[0]);
    tq[1] = __fdividef(xf[1], wd[1]);
    const f32x2 t  = tq + 0.5f;
    const f32x2 tc = __builtin_elementwise_min(__builtin_elementwise_max(t, zero), one);
    const f32x2 s  = one - tc;

    // P = sum_{i=1..10} C10_i cn_[i] tc^i s^(10-i); Q = sum C9_i spv[i] tc^i s^(9-i)
    const float C10[11] = {1.f,10.f,45.f,120.f,210.f,252.f,210.f,120.f,45.f,10.f,1.f};
    const float C9[10]  = {1.f,9.f,36.f,84.f,126.f,126.f,84.f,36.f,9.f,1.f};
    f32x2 tk = one, P = zero, Q = zero;
#pragma unroll
    for (int i = 0; i < 10; ++i) {
        Q = __builtin_elementwise_fma(Q, s, tk * (spv[i] * C9[i]));   // pk_fma + 2 pk_mul
        P = __builtin_elementwise_fma(P, s, tk * (cn_[i] * C10[i]));
        tk = tk * tc;                                                  // pk_mul
    }
    P = __builtin_elementwise_fma(P, s, tk * cn_[10]);                 // i=10, C=1

    const f32x2 der = (Q * 10.f) * inv;
    const f32x2 ym  = P * inv;

    f32x2 y;
#pragma unroll
    for (int k = 0; k < 2; ++k) {
        const float yk = (t[k] < 0.f) ? (t[k] * der[k])
                       : ((t[k] > 1.f) ? fmaf(t[k] - 1.f, der[k], 1.f) : ym[k]);
        y[k] = (yk - 0.5f) * hg[k];
    }
    return y;
}

// fallback math (R3-proven de Casteljau)
__device__ __forceinline__ float softplus_f(float x) {
    return __logf(1.0f + __expf(x));
}
__device__ __forceinline__ float spline_eval(const float* sv, float xf) {
    float cn[11];
    cn[0] = 0.f;
    float run = 0.f;
#pragma unroll
    for (int j = 0; j < 10; ++j) { run += softplus_f(sv[j]); cn[j + 1] = run; }
    const float inv = __fdividef(1.f, run);
    const float wd = softplus_f(sv[10]) + 0.1f;
    float hg = sv[11];
    hg += 0.1f * sgn01(hg);
    const float t   = __fdividef(xf, wd) + 0.5f;
    const float tc  = fminf(fmaxf(t, 0.f), 1.f);
#pragma unroll
    for (int n = 10; n >= 2; --n) {
#pragma unroll
        for (int i = 0; i < n; ++i) cn[i] += tc * (cn[i + 1] - cn[i]);
    }
    const float db    = cn[1] - cn[0];
    const float deriv = 10.f * db * inv;
    const float ym    = fmaf(tc, db, cn[0]) * inv;
    float y = (t < 0.f) ? (t * deriv)
            : ((t > 1.f) ? fmaf(t - 1.f, deriv, 1.f) : ym);
    return (y - 0.5f) * hg;
}

// ---- prep: split W f32 -> bf16 hi/lo (RNE both) in B-fragment order ----
// frag layout: [(k>>3)*3072 + out*8 + (k&7)], hi at wsH, lo at wsL
__global__ void prep_w(const float* __restrict__ W, short* __restrict__ wsH,
                       short* __restrict__ wsL) {
    const int g = blockIdx.x * 256 + threadIdx.x;
    if (g < 12288) {
        const int o = g >> 5;        // W row (out index 0..383)
        const int k = g & 31;
        const float w = W[g];
        const short hi = f2bf(w);
        const int off = (k >> 3) * 3072 + o * 8 + (k & 7);
        wsH[off] = hi;
        wsL[off] = f2bf(w - bf2f(hi));
    }
}

// ---- main: 2048 blocks = (row group) x (channel half), 4 waves, no barriers ----
__global__ __launch_bounds__(256) void bern_spline_fast(
    const float* __restrict__ x, const short* __restrict__ wsH,
    const short* __restrict__ wsL, const float* __restrict__ bias,
    float* __restrict__ out)
{
    __shared__ __align__(16) float sl[4 * 16 * 100];  // per-wave 16x(96+4pad), 25.6 KB

    const int tid  = threadIdx.x;
    const int wave = tid >> 6;
    const int lane = tid & 63;
    const int cbit = blockIdx.x & 1;            // channel half: ch in [cbit*16, +16)
    const int block_row = (blockIdx.x >> 1) * 64;

    const int row16 = lane & 15;
    const int kq    = lane >> 4;
    const int arow  = block_row + wave * 16 + row16;

    // xf pairs for both halves — issued first, consumed deep in spline phase
    const int cg0_h0 = cbit * 16 + 2 * kq;
    const f32x2 xf2_0 = *(const f32x2*)(x + (size_t)arow * 64 + 32 + cg0_h0);
    const f32x2 xf2_1 = *(const f32x2*)(x + (size_t)arow * 64 + 32 + cg0_h0 + 8);

    // A fragment: lane holds x1[row = l&15][k = (l>>4)*8 .. +7], RNE hi+lo split
    const f32x4 a0 = *(const f32x4*)(x + (size_t)arow * 64 + kq * 8);
    const f32x4 a1 = *(const f32x4*)(x + (size_t)arow * 64 + kq * 8 + 4);
    v8s ah, al;
#pragma unroll
    for (int e = 0; e < 4; ++e) {
        const short h0 = f2bf(a0[e]);
        ah[e] = h0;     al[e] = f2bf(a0[e] - bf2f(h0));
        const short h1 = f2bf(a1[e]);
        ah[e + 4] = h1; al[e + 4] = f2bf(a1[e] - bf2f(h1));
    }

    // ---- x1 passthrough directly from A-fragment registers (even blocks) ----
    if (cbit == 0) {
        *(f32x4*)(out + (size_t)arow * 64 + kq * 8)     = a0;
        *(f32x4*)(out + (size_t)arow * 64 + kq * 8 + 4) = a1;
    }

    // bias per C tile: constant along batch-row dim -> MFMA C-in {bv,bv,bv,bv}
    float bv0[6], bv1[6];
#pragma unroll
    for (int ot = 0; ot < 6; ++ot) {
        bv0[ot] = bias[(cbit * 12 + ot) * 16 + row16];
        bv1[ot] = bias[(cbit * 12 + 6 + ot) * 16 + row16];
    }

    float* swv = sl + wave * 1600;   // wave-private transpose buffer

    // ---- B-frag loads, BOTH halves up front (L2 latency overlapped) ----
    v8s bh0[6], bl0[6], bh1[6], bl1[6];
#pragma unroll
    for (int ot = 0; ot < 6; ++ot) {
        const int boff0 = kq * 3072 + ((cbit * 12 + ot) * 16 + row16) * 8;
        const int boff1 = kq * 3072 + ((cbit * 12 + 6 + ot) * 16 + row16) * 8;
        bh0[ot] = *(const v8s*)(wsH + boff0);
        bl0[ot] = *(const v8s*)(wsL + boff0);
        bh1[ot] = *(const v8s*)(wsH + boff1);
        bl1[ot] = *(const v8s*)(wsL + boff1);
    }

    // ---- MFMA half 0 (bias in C) + LDS scatter ----
#pragma unroll
    for (int ot = 0; ot < 6; ++ot) {
        f32x4 cb; cb[0] = bv0[ot]; cb[1] = bv0[ot]; cb[2] = bv0[ot]; cb[3] = bv0[ot];
        f32x4 c = __builtin_amdgcn_mfma_f32_16x16x32_bf16(al, bh0[ot], cb, 0, 0, 0);
        c = __builtin_amdgcn_mfma_f32_16x16x32_bf16(ah, bl0[ot], c, 0, 0, 0);
        c = __builtin_amdgcn_mfma_f32_16x16x32_bf16(ah, bh0[ot], c, 0, 0, 0);
#pragma unroll
        for (int r = 0; r < 4; ++r)
            swv[(kq * 4 + r) * 100 + ot * 16 + row16] = c[r];
    }

    // ---- read sv0 into registers (the one exposed LDS round trip) ----
    const float* sp = swv + row16 * 100 + 2 * kq * 12;
    const f32x4 vA00 = *(const f32x4*)(sp);
    const f32x4 vA01 = *(const f32x4*)(sp + 4);
    const f32x4 vA02 = *(const f32x4*)(sp + 8);
    const f32x4 vB00 = *(const f32x4*)(sp + 12);
    const f32x4 vB01 = *(const f32x4*)(sp + 16);
    const f32x4 vB02 = *(const f32x4*)(sp + 20);

    // ---- MFMA half 1 into registers (no LDS touch -> legal before spline0) ----
    f32x4 c10, c11, c12, c13, c14, c15;
    {
        f32x4 cb;
#define MFMA_H1(CC, OT) \
        cb[0] = bv1[OT]; cb[1] = bv1[OT]; cb[2] = bv1[OT]; cb[3] = bv1[OT]; \
        CC = __builtin_amdgcn_mfma_f32_16x16x32_bf16(al, bh1[OT], cb, 0, 0, 0); \
        CC = __builtin_amdgcn_mfma_f32_16x16x32_bf16(ah, bl1[OT], CC, 0, 0, 0); \
        CC = __builtin_amdgcn_mfma_f32_16x16x32_bf16(ah, bh1[OT], CC, 0, 0, 0);
        MFMA_H1(c10, 0) MFMA_H1(c11, 1) MFMA_H1(c12, 2)
        MFMA_H1(c13, 3) MFMA_H1(c14, 4) MFMA_H1(c15, 5)
#undef MFMA_H1
    }

    // ---- write1 (after sv0 is safely in regs) ----
#pragma unroll
    for (int r = 0; r < 4; ++r) {
        swv[(kq * 4 + r) * 100 +  0 + row16] = c10[r];
        swv[(kq * 4 + r) * 100 + 16 + row16] = c11[r];
        swv[(kq * 4 + r) * 100 + 32 + row16] = c12[r];
        swv[(kq * 4 + r) * 100 + 48 + row16] = c13[r];
        swv[(kq * 4 + r) * 100 + 64 + row16] = c14[r];
        swv[(kq * 4 + r) * 100 + 80 + row16] = c15[r];
    }

    // ---- issue sv1 reads NOW; latency hides under spline0's VALU chain ----
    const f32x4 vA10 = *(const f32x4*)(sp);
    const f32x4 vA11 = *(const f32x4*)(sp + 4);
    const f32x4 vA12 = *(const f32x4*)(sp + 8);
    const f32x4 vB10 = *(const f32x4*)(sp + 12);
    const f32x4 vB11 = *(const f32x4*)(sp + 16);
    const f32x4 vB12 = *(const f32x4*)(sp + 20);

    // ---- spline half 0 (packed A,B pair) ----
    {
        f32x2 sv2[12];
#pragma unroll
        for (int e = 0; e < 4; ++e) {
            sv2[e][0]     = vA00[e]; sv2[e][1]     = vB00[e];
            sv2[e + 4][0] = vA01[e]; sv2[e + 4][1] = vB01[e];
            sv2[e + 8][0] = vA02[e]; sv2[e + 8][1] = vB02[e];
        }
        const f32x2 y2 = spline_horner2(sv2, xf2_0);
        *(f32x2*)(out + (size_t)arow * 64 + 32 + cg0_h0) = y2;
    }

    // ---- spline half 1 (packed A,B pair) ----
    {
        f32x2 sv2[12];
#pragma unroll
        for (int e = 0; e < 4; ++e) {
            sv2[e][0]     = vA10[e]; sv2[e][1]     = vB10[e];
            sv2[e + 4][0] = vA11[e]; sv2[e + 4][1] = vB11[e];
            sv2[e + 8][0] = vA12[e]; sv2[e + 8][1] = vB12[e];
        }
        const f32x2 y2 = spline_horner2(sv2, xf2_1);
        *(f32x2*)(out + (size_t)arow * 64 + 32 + cg0_h0 + 8) = y2;
    }
}

// ---- fallback (R3 structure, known-pass): used only if ws is too small ----
__global__ __launch_bounds__(256) void bern_spline_fallback(
    const float* __restrict__ x, const float* __restrict__ W,
    const float* __restrict__ bias, float* __restrict__ out)
{
    __shared__ short Wh[12288];
    __shared__ short Wl[12288];
    __shared__ float bl[384];
    __shared__ float sl[4 * 16 * 100];

    const int tid  = threadIdx.x;
    const int wave = tid >> 6;
    const int lane = tid & 63;
    const int block_row = blockIdx.x * 64;

    for (int g = tid; g < 12288; g += 256) {
        const int o = g >> 5;
        const int k = g & 31;
        const float w = W[g];
        const short hi = f2bf(w);
        Wh[(k >> 3) * 3072 + o * 8 + (k & 7)] = hi;
        Wl[(k >> 3) * 3072 + o * 8 + (k & 7)] = f2bf(w - bf2f(hi));
    }
    for (int g = tid; g < 384; g += 256) bl[g] = bias[g];
    __syncthreads();

    for (int i = tid; i < 512; i += 256) {
        const int r = i >> 3, q = i & 7;
        *(f32x4*)(out + (size_t)(block_row + r) * 64 + q * 4) =
            *(const f32x4*)(x + (size_t)(block_row + r) * 64 + q * 4);
    }

    const int row16 = lane & 15;
    const int kq    = lane >> 4;
    const int arow  = block_row + wave * 16 + row16;
    const f32x4 a0 = *(const f32x4*)(x + (size_t)arow * 64 + kq * 8);
    const f32x4 a1 = *(const f32x4*)(x + (size_t)arow * 64 + kq * 8 + 4);
    v8s ah, al;
#pragma unroll
    for (int e = 0; e < 4; ++e) {
        const short h0 = f2bf(a0[e]);
        ah[e] = h0;     al[e] = f2bf(a0[e] - bf2f(h0));
        const short h1 = f2bf(a1[e]);
        ah[e + 4] = h1; al[e + 4] = f2bf(a1[e] - bf2f(h1));
    }

    float* swv = sl + wave * 1600;
    const f32x4 zero4 = {0.f, 0.f, 0.f, 0.f};

    for (int qt = 0; qt < 4; ++qt) {
        f32x4 acc[6];
#pragma unroll
        for (int ot = 0; ot < 6; ++ot) {
            const int otg = qt * 6 + ot;
            const int boff = kq * 3072 + (otg * 16 + row16) * 8;
            const v8s bh  = *(const v8s*)(Wh + boff);
            const v8s blo = *(const v8s*)(Wl + boff);
            f32x4 c = __builtin_amdgcn_mfma_f32_16x16x32_bf16(al, bh, zero4, 0, 0, 0);
            c = __builtin_amdgcn_mfma_f32_16x16x32_bf16(ah, blo, c, 0, 0, 0);
            acc[ot] = __builtin_amdgcn_mfma_f32_16x16x32_bf16(ah, bh, c, 0, 0, 0);
        }
#pragma unroll
        for (int ot = 0; ot < 6; ++ot)
#pragma unroll
            for (int r = 0; r < 4; ++r)
                swv[(kq * 4 + r) * 100 + ot * 16 + row16] = acc[ot][r];

#pragma unroll
        for (int p = 0; p < 2; ++p) {
            const int idx = p * 64 + lane;
            const int cl  = idx & 7;
            const int rr  = idx >> 3;
            const int cg  = qt * 8 + cl;

            const float* sp = swv + rr * 100 + cl * 12;
            const f32x4 s0 = *(const f32x4*)(sp);
            const f32x4 s1 = *(const f32x4*)(sp + 4);
            const f32x4 s2 = *(const f32x4*)(sp + 8);
            const f32x4 b0 = *(const f32x4*)(bl + cg * 12);
            const f32x4 b1 = *(const f32x4*)(bl + cg * 12 + 4);
            const f32x4 b2 = *(const f32x4*)(bl + cg * 12 + 8);

            float sv[12];
            sv[0]  = s0[0] + b0[0]; sv[1]  = s0[1] + b0[1];
            sv[2]  = s0[2] + b0[2]; sv[3]  = s0[3] + b0[3];
            sv[4]  = s1[0] + b1[0]; sv[5]  = s1[1] + b1[1];
            sv[6]  = s1[2] + b1[2]; sv[7]  = s1[3] + b1[3];
            sv[8]  = s2[0] + b2[0]; sv[9]  = s2[1] + b2[1];
            sv[10] = s2[2] + b2[2]; sv[11] = s2[3] + b2[3];

            const int rowg = block_row + wave * 16 + rr;
            const float xf = x[(size_t)rowg * 64 + 32 + cg];
            out[(size_t)rowg * 64 + 32 + cg] = spline_eval(sv, xf);
        }
    }
}

extern "C" void kernel_launch(void* const* d_in, const int* in_sizes, int n_in,
                              void* d_out, int out_size, void* d_ws, size_t ws_size,
                              hipStream_t stream) {
    const float* x = (const float*)d_in[0];
    const float* W = (const float*)d_in[1];
    const float* b = (const float*)d_in[2];
    float* out = (float*)d_out;

    if (d_ws != nullptr && ws_size >= 49152) {
        short* wsH = (short*)d_ws;
        short* wsL = wsH + 12288;
        prep_w<<<48, 256, 0, stream>>>(W, wsH, wsL);                     // 48 KB, L2-resident
        bern_spline_fast<<<2048, 256, 0, stream>>>(x, wsH, wsL, b, out); // 64 rows x 16 ch
    } else {
        bern_spline_fallback<<<1024, 256, 0, stream>>>(x, W, b, out);
    }
}